// Round 6
// baseline (70.324 us; speedup 1.0000x reference)
//
#include <hip/hip_runtime.h>
#include <hip/hip_cooperative_groups.h>
#include <math.h>

namespace cg = cooperative_groups;

// Problem constants (match reference)
#define B_ 2
#define T_ 2048
#define M_ 768
#define R_ 64
#define S_ 16
#define MS_ (M_ * S_)
#define LOG_EPS_F (-23.025850929940457f)

// ---------------- fused cooperative kernel config ----------------
#define FNC 64             // t-chunks
#define FCL 32             // T_/FNC steps per chunk
#define MT  128            // m per block
#define NMT 6              // M_/MT
#define FGRID (B_ * FNC * NMT)   // 768 blocks, 3/CU
#define PITCH 132          // padded LDS row pitch (breaks row-stride bank conflicts)

// --------------------------------------------------------------------------
// Fused kernel: dt-GEMM -> bc partials -> bc reduce -> local scan -> carry ->
// replay. One block = (b, chunk, m-tile). dt/u/Bm/Cm tiles stay resident in
// LDS across all phases (grid syncs preserve LDS).
// --------------------------------------------------------------------------
__global__ __launch_bounds__(256, 3) void fused_kernel(
    const float* __restrict__ u, const float* __restrict__ delta,
    const float* __restrict__ dt_w, const float* __restrict__ dt_b,
    const float* __restrict__ A_log, const float* __restrict__ B_w,
    const float* __restrict__ C_w, const float* __restrict__ D,
    float* __restrict__ out,
    float* __restrict__ part,    // [128 bc][32 t][32 s2][8 mt-pad]
    float* __restrict__ Bm_g,    // [4096][16]
    float* __restrict__ Cm_g,    // [4096][16]
    float* __restrict__ Aprod,   // [128 bc][16 s][768 m]; carry after S4
    float* __restrict__ Hend)    // [128 bc][16 s][768 m]
{
  __shared__ float u_lds[FCL][PITCH];
  __shared__ float dt_lds[FCL][PITCH];
  __shared__ float scratch[4224];  // delta_s[32][68] | W_lds[32][132] | bm[512]+cm[512]

  cg::grid_group grid = cg::this_grid();

  const int tid = threadIdx.x;
  const int bid = blockIdx.x;
  const int mt  = bid % NMT;
  const int bc  = bid / NMT;           // b*64 + c
  const int m0  = mt * MT;
  const size_t row0 = (size_t)bc * FCL;  // global bt row base (b*2048 + c*32)

  // ---- stage delta_s (scratch) + u_lds ----
  {
    float (*delta_s)[68] = reinterpret_cast<float (*)[68]>(scratch);
    #pragma unroll
    for (int p = 0; p < 2; ++p) {
      const int i4 = tid + p * 256;            // 512 float4
      const int t = i4 >> 4, c4 = (i4 & 15) * 4;
      *reinterpret_cast<float4*>(&delta_s[t][c4]) =
          *reinterpret_cast<const float4*>(&delta[(row0 + t) * R_ + c4]);
    }
    #pragma unroll
    for (int p = 0; p < 4; ++p) {
      const int i4 = tid + p * 256;            // 1024 float4
      const int t = i4 >> 5, c4 = (i4 & 31) * 4;
      *reinterpret_cast<float4*>(&u_lds[t][c4]) =
          *reinterpret_cast<const float4*>(&u[(row0 + t) * M_ + m0 + c4]);
    }
  }
  __syncthreads();

  // ---- 0a: dt tile = clip(softplus(delta_s . dt_w^T + b)) -> dt_lds ----
  {
    float (*delta_s)[68] = reinterpret_cast<float (*)[68]>(scratch);
    const int ml = tid & 127, th = tid >> 7;   // th: t-half
    float acc[16] = {};
    const float* wrow = &dt_w[(size_t)(m0 + ml) * R_];
    #pragma unroll
    for (int r4 = 0; r4 < R_; r4 += 4) {
      const float4 w4 = *reinterpret_cast<const float4*>(&wrow[r4]);
      #pragma unroll
      for (int i = 0; i < 16; ++i) {
        const float4 d4 = *reinterpret_cast<const float4*>(&delta_s[th * 16 + i][r4]);
        acc[i] = fmaf(d4.x, w4.x, acc[i]);
        acc[i] = fmaf(d4.y, w4.y, acc[i]);
        acc[i] = fmaf(d4.z, w4.z, acc[i]);
        acc[i] = fmaf(d4.w, w4.w, acc[i]);
      }
    }
    const float bias = dt_b[m0 + ml];
    #pragma unroll
    for (int i = 0; i < 16; ++i) {
      const float x = acc[i] + bias;
      const float sp = (x > 20.f) ? x : __logf(1.f + __expf(x));
      dt_lds[th * 16 + i][ml] = fminf(fmaxf(sp, 1e-6f), 10.f);
    }
  }
  __syncthreads();   // delta_s dead

  // ---- stage W tile (32 s2 rows x 128 m) into scratch ----
  {
    float (*W_lds)[PITCH] = reinterpret_cast<float (*)[PITCH]>(scratch);
    #pragma unroll
    for (int p = 0; p < 4; ++p) {
      const int i4 = tid + p * 256;            // 1024 float4
      const int s2 = i4 >> 5, c4 = (i4 & 31) * 4;
      const float* src = (s2 < 16) ? &B_w[(size_t)s2 * M_] : &C_w[(size_t)(s2 - 16) * M_];
      *reinterpret_cast<float4*>(&W_lds[s2][c4]) =
          *reinterpret_cast<const float4*>(&src[m0 + c4]);
    }
  }
  __syncthreads();

  // ---- 0b: partial Bm/Cm over this block's 128 m -> part ----
  {
    float (*W_lds)[PITCH] = reinterpret_cast<float (*)[PITCH]>(scratch);
    const int t = tid >> 3, sq = tid & 7;
    float acc[4] = {};
    #pragma unroll
    for (int k4 = 0; k4 < MT; k4 += 4) {
      const float4 uv = *reinterpret_cast<const float4*>(&u_lds[t][k4]);
      #pragma unroll
      for (int j = 0; j < 4; ++j) {
        const float4 wv = *reinterpret_cast<const float4*>(&W_lds[sq + 8 * j][k4]);
        acc[j] = fmaf(uv.x, wv.x, acc[j]);
        acc[j] = fmaf(uv.y, wv.y, acc[j]);
        acc[j] = fmaf(uv.z, wv.z, acc[j]);
        acc[j] = fmaf(uv.w, wv.w, acc[j]);
      }
    }
    #pragma unroll
    for (int j = 0; j < 4; ++j) {
      const int s2 = sq + 8 * j;
      part[(((size_t)bc * FCL + t) * 32 + s2) * 8 + mt] = acc[j];
    }
  }
  grid.sync();   // S1

  // ---- 0c: reduce partials over 6 m-tiles -> global Bm/Cm (mt==0 blocks) ----
  if (mt == 0) {
    for (int o = tid; o < FCL * 32; o += 256) {
      const int t = o >> 5, s2 = o & 31;
      const float* p = &part[(((size_t)bc * FCL + t) * 32 + s2) * 8];
      const float v = ((p[0] + p[1]) + (p[2] + p[3])) + (p[4] + p[5]);
      const size_t bt = row0 + t;
      if (s2 < 16) Bm_g[bt * S_ + s2] = v;
      else         Cm_g[bt * S_ + (s2 - 16)] = v;
    }
  }
  grid.sync();   // S2

  // ---- stage bm/cm into scratch (W dead); compute Acol ----
  float* bm_lds = scratch;          // [32 t][16 s]
  float* cm_lds = scratch + 512;
  for (int idx = tid; idx < FCL * S_; idx += 256) {
    bm_lds[idx] = Bm_g[row0 * S_ + idx];
    cm_lds[idx] = Cm_g[row0 * S_ + idx];
  }

  const int ml = (tid >> 6) * 32 + (tid & 31);   // 0..127
  const int sh = (tid >> 5) & 1, s0 = sh * 8;
  const int m = m0 + ml;

  float Acol[8];
  #pragma unroll
  for (int s = 0; s < 8; ++s) {
    const float a = -__expf(A_log[(size_t)(s0 + s) * M_ + m]);
    Acol[s] = fminf(fmaxf(a, -10.f), -1e-6f);
  }
  __syncthreads();

  // ---- phase 1: local scan (h_in = 0), record P & Hend ----
  const size_t smb = ((size_t)bc * S_ + s0) * M_ + m;
  {
    float h[8], P[8];
    #pragma unroll
    for (int s = 0; s < 8; ++s) { h[s] = 0.f; P[s] = 1.f; }
    #pragma unroll 8
    for (int t = 0; t < FCL; ++t) {
      const float dtv = dt_lds[t][ml];
      const float uv  = u_lds[t][ml];
      const float du  = dtv * uv;
      const float4 bv0 = *reinterpret_cast<const float4*>(&bm_lds[t * S_ + s0]);
      const float4 bv1 = *reinterpret_cast<const float4*>(&bm_lds[t * S_ + s0 + 4]);
      const float bmv[8] = {bv0.x, bv0.y, bv0.z, bv0.w, bv1.x, bv1.y, bv1.z, bv1.w};
      #pragma unroll
      for (int s = 0; s < 8; ++s) {
        const float la = fmaxf(dtv * Acol[s], LOG_EPS_F);
        const float e = __expf(la);
        h[s] = fmaf(e, h[s], du * bmv[s]);
        P[s] *= e;
      }
    }
    #pragma unroll
    for (int s = 0; s < 8; ++s) {
      Aprod[smb + (size_t)s * M_] = P[s];
      Hend[smb + (size_t)s * M_]  = h[s];
    }
  }
  grid.sync();   // S3

  // ---- carry combine (96 blocks), in place: Aprod[c] <- carry into chunk c --
  if (bid < (B_ * MS_) / 256) {
    const int idx = bid * 256 + tid;            // over B*S*M
    const int b2 = idx / MS_;
    const int sm = idx - b2 * MS_;
    float h = 0.f;
    #pragma unroll 8
    for (int cc = 0; cc < FNC; ++cc) {
      const size_t o = ((size_t)b2 * FNC + cc) * MS_ + sm;
      const float a  = Aprod[o];
      const float he = Hend[o];
      Aprod[o] = h;
      h = fmaf(a, h, he);
    }
  }
  grid.sync();   // S4

  // ---- phase 3: replay with carry, produce out (LDS tiles still resident) --
  {
    float h[8];
    #pragma unroll
    for (int s = 0; s < 8; ++s) h[s] = Aprod[smb + (size_t)s * M_];
    const float Dm = D[m];
    #pragma unroll 8
    for (int t = 0; t < FCL; ++t) {
      const float dtv = dt_lds[t][ml];
      const float uv  = u_lds[t][ml];
      const float du  = dtv * uv;
      const float4 bv0 = *reinterpret_cast<const float4*>(&bm_lds[t * S_ + s0]);
      const float4 bv1 = *reinterpret_cast<const float4*>(&bm_lds[t * S_ + s0 + 4]);
      const float bmv[8] = {bv0.x, bv0.y, bv0.z, bv0.w, bv1.x, bv1.y, bv1.z, bv1.w};
      const float4 cv0 = *reinterpret_cast<const float4*>(&cm_lds[t * S_ + s0]);
      const float4 cv1 = *reinterpret_cast<const float4*>(&cm_lds[t * S_ + s0 + 4]);
      const float cmv[8] = {cv0.x, cv0.y, cv0.z, cv0.w, cv1.x, cv1.y, cv1.z, cv1.w};
      float y = 0.f;
      #pragma unroll
      for (int s = 0; s < 8; ++s) {
        const float la = fmaxf(dtv * Acol[s], LOG_EPS_F);
        const float e = __expf(la);
        h[s] = fmaf(e, h[s], du * bmv[s]);
        y = fmaf(h[s], cmv[s], y);
      }
      y += __shfl_xor(y, 32);
      if (sh == 0) {
        const float o = y + uv * Dm;
        out[(row0 + t) * M_ + m] = fminf(fmaxf(o, -1e4f), 1e4f);
      }
    }
  }
}

// ==========================================================================
// Fallback path (round-5 verified 5-kernel pipeline), used only if the
// cooperative grid cannot be co-resident.
// ==========================================================================
#define NCF 128
#define CLF (T_ / NCF)

__global__ __launch_bounds__(256) void dt_kernel(
    const float* __restrict__ delta, const float* __restrict__ dt_w,
    const float* __restrict__ dt_b, float* __restrict__ dt_out)
{
  __shared__ float ds_d[R_][68];
  __shared__ float ds_w[R_][68];
  const int tid = threadIdx.x;
  const int m0  = blockIdx.x * 64;
  const int bt0 = blockIdx.y * 64;
  #pragma unroll
  for (int k = 0; k < 4; ++k) {
    int idx = tid + k * 256;
    int rq = idx & 15;
    int x  = idx >> 4;
    float4 dv = *reinterpret_cast<const float4*>(&delta[(size_t)(bt0 + x) * R_ + rq * 4]);
    ds_d[rq * 4 + 0][x] = dv.x; ds_d[rq * 4 + 1][x] = dv.y;
    ds_d[rq * 4 + 2][x] = dv.z; ds_d[rq * 4 + 3][x] = dv.w;
    float4 wv = *reinterpret_cast<const float4*>(&dt_w[(size_t)(m0 + x) * R_ + rq * 4]);
    ds_w[rq * 4 + 0][x] = wv.x; ds_w[rq * 4 + 1][x] = wv.y;
    ds_w[rq * 4 + 2][x] = wv.z; ds_w[rq * 4 + 3][x] = wv.w;
  }
  __syncthreads();
  const int mq = tid & 15, tq = tid >> 4;
  const int mlq = mq * 4, tl = tq * 4;
  float acc[4][4] = {};
  #pragma unroll 4
  for (int r = 0; r < R_; ++r) {
    float4 dv = *reinterpret_cast<const float4*>(&ds_d[r][tl]);
    float4 wv = *reinterpret_cast<const float4*>(&ds_w[r][mlq]);
    float d[4] = {dv.x, dv.y, dv.z, dv.w};
    float w[4] = {wv.x, wv.y, wv.z, wv.w};
    #pragma unroll
    for (int i = 0; i < 4; ++i)
      #pragma unroll
      for (int j = 0; j < 4; ++j)
        acc[i][j] = fmaf(d[i], w[j], acc[i][j]);
  }
  float4 bb = *reinterpret_cast<const float4*>(&dt_b[m0 + mlq]);
  float bv[4] = {bb.x, bb.y, bb.z, bb.w};
  #pragma unroll
  for (int i = 0; i < 4; ++i) {
    float4 o;
    float* op = &o.x;
    #pragma unroll
    for (int j = 0; j < 4; ++j) {
      float x = acc[i][j] + bv[j];
      float sp = (x > 20.f) ? x : __logf(1.f + __expf(x));
      op[j] = fminf(fmaxf(sp, 1e-6f), 10.f);
    }
    *reinterpret_cast<float4*>(&dt_out[(size_t)(bt0 + tl + i) * M_ + m0 + mlq]) = o;
  }
}

__global__ __launch_bounds__(512, 4) void bc_kernel(
    const float* __restrict__ u, const float* __restrict__ B_w,
    const float* __restrict__ C_w, float* __restrict__ Bm, float* __restrict__ Cm)
{
  const int wave = threadIdx.x >> 6, lane = threadIdx.x & 63;
  const int bt0 = blockIdx.x * 8;
  float4 w[4][3];
  #pragma unroll
  for (int s = 0; s < 4; ++s) {
    const int s_g = wave * 4 + s;
    const float* wr = (s_g < 16) ? &B_w[(size_t)s_g * M_] : &C_w[(size_t)(s_g - 16) * M_];
    const float4* w4 = reinterpret_cast<const float4*>(wr);
    w[s][0] = w4[lane]; w[s][1] = w4[64 + lane]; w[s][2] = w4[128 + lane];
  }
  float acc[32];
  #pragma unroll
  for (int r = 0; r < 8; ++r) {
    const float4* ur = reinterpret_cast<const float4*>(&u[(size_t)(bt0 + r) * M_]);
    const float4 a0 = ur[lane], a1 = ur[64 + lane], a2 = ur[128 + lane];
    #pragma unroll
    for (int s = 0; s < 4; ++s) {
      float t = 0.f;
      t = fmaf(a0.x, w[s][0].x, t); t = fmaf(a0.y, w[s][0].y, t);
      t = fmaf(a0.z, w[s][0].z, t); t = fmaf(a0.w, w[s][0].w, t);
      t = fmaf(a1.x, w[s][1].x, t); t = fmaf(a1.y, w[s][1].y, t);
      t = fmaf(a1.z, w[s][1].z, t); t = fmaf(a1.w, w[s][1].w, t);
      t = fmaf(a2.x, w[s][2].x, t); t = fmaf(a2.y, w[s][2].y, t);
      t = fmaf(a2.z, w[s][2].z, t); t = fmaf(a2.w, w[s][2].w, t);
      acc[r * 4 + s] = t;
    }
  }
  #pragma unroll
  for (int j = 0; j < 32; ++j) acc[j] += __shfl_xor(acc[j], 32);
  int cnt = 32;
  #pragma unroll
  for (int mask = 16; mask >= 1; mask >>= 1) {
    cnt >>= 1;
    const bool up = (lane & mask) != 0;
    #pragma unroll
    for (int j = 0; j < cnt; ++j) {
      float give = up ? acc[j] : acc[j + cnt];
      float keep = up ? acc[j + cnt] : acc[j];
      acc[j] = keep + __shfl_xor(give, mask);
    }
  }
  if (lane < 32) {
    const int r = lane >> 2, s_l = lane & 3;
    const int s_g = wave * 4 + s_l;
    const int bt = bt0 + r;
    if (s_g < 16) Bm[(size_t)bt * S_ + s_g] = acc[0];
    else          Cm[(size_t)bt * S_ + (s_g - 16)] = acc[0];
  }
}

template <int PHASE>
__global__ __launch_bounds__(128) void scan_kernel(
    const float* __restrict__ dt_ws, const float* __restrict__ u,
    const float* __restrict__ Bm, const float* __restrict__ Cm,
    const float* __restrict__ A_log, const float* __restrict__ D,
    float* __restrict__ Aprod, float* __restrict__ Hend, float* __restrict__ out)
{
  __shared__ float dt_lds[CLF][64];
  __shared__ float u_lds[CLF][64];
  __shared__ float lds_bm[CLF * S_];
  __shared__ float lds_cm[CLF * S_];
  const int tid = threadIdx.x;
  const int lane = tid & 63, wv = tid >> 6;
  const int m_l = wv * 32 + (lane & 31);
  const int sh = lane >> 5, s0 = sh * 8;
  const int m = blockIdx.x * 64 + m_l;
  const int c = blockIdx.y, b = blockIdx.z;
  const int t0 = c * CLF;
  const size_t gbase = ((size_t)b * T_ + t0) * M_ + blockIdx.x * 64;
  #pragma unroll
  for (int p = 0; p < CLF * 16 / 128; ++p) {
    const int i4 = tid + p * 128;
    const int t = i4 >> 4, m4 = (i4 & 15) * 4;
    *reinterpret_cast<float4*>(&dt_lds[t][m4]) =
        *reinterpret_cast<const float4*>(&dt_ws[gbase + (size_t)t * M_ + m4]);
    *reinterpret_cast<float4*>(&u_lds[t][m4]) =
        *reinterpret_cast<const float4*>(&u[gbase + (size_t)t * M_ + m4]);
  }
  {
    const size_t bcb = ((size_t)b * T_ + t0) * S_;
    #pragma unroll
    for (int p = 0; p < CLF * S_ / 128; ++p) {
      const int idx = tid + p * 128;
      lds_bm[idx] = Bm[bcb + idx];
      if constexpr (PHASE == 3) lds_cm[idx] = Cm[bcb + idx];
    }
  }
  float Acol[8];
  #pragma unroll
  for (int s = 0; s < 8; ++s) {
    float a = -__expf(A_log[(size_t)(s0 + s) * M_ + m]);
    Acol[s] = fminf(fmaxf(a, -10.f), -1e-6f);
  }
  float h[8], P[8], Dm = 0.f;
  const size_t smb = (((size_t)b * NCF + c) * S_ + s0) * M_ + m;
  if constexpr (PHASE == 1) {
    #pragma unroll
    for (int s = 0; s < 8; ++s) { h[s] = 0.f; P[s] = 1.f; }
  } else {
    #pragma unroll
    for (int s = 0; s < 8; ++s) h[s] = Aprod[smb + (size_t)s * M_];
    Dm = D[m];
  }
  __syncthreads();
  const size_t g0 = ((size_t)b * T_ + t0) * M_ + m;
  #pragma unroll 8
  for (int t = 0; t < CLF; ++t) {
    const float dtv = dt_lds[t][m_l];
    const float uv  = u_lds[t][m_l];
    const float du  = dtv * uv;
    const float4 bv0 = *reinterpret_cast<const float4*>(&lds_bm[t * S_ + s0]);
    const float4 bv1 = *reinterpret_cast<const float4*>(&lds_bm[t * S_ + s0 + 4]);
    const float bmv[8] = {bv0.x, bv0.y, bv0.z, bv0.w, bv1.x, bv1.y, bv1.z, bv1.w};
    float cmv[8];
    if constexpr (PHASE == 3) {
      const float4 cv0 = *reinterpret_cast<const float4*>(&lds_cm[t * S_ + s0]);
      const float4 cv1 = *reinterpret_cast<const float4*>(&lds_cm[t * S_ + s0 + 4]);
      cmv[0] = cv0.x; cmv[1] = cv0.y; cmv[2] = cv0.z; cmv[3] = cv0.w;
      cmv[4] = cv1.x; cmv[5] = cv1.y; cmv[6] = cv1.z; cmv[7] = cv1.w;
    }
    float y = 0.f;
    #pragma unroll
    for (int s = 0; s < 8; ++s) {
      float la = fmaxf(dtv * Acol[s], LOG_EPS_F);
      float e = __expf(la);
      h[s] = fmaf(e, h[s], du * bmv[s]);
      if constexpr (PHASE == 1) P[s] *= e;
      else y = fmaf(h[s], cmv[s], y);
    }
    if constexpr (PHASE == 3) {
      y += __shfl_xor(y, 32);
      if (sh == 0) {
        float o = y + uv * Dm;
        out[g0 + (size_t)t * M_] = fminf(fmaxf(o, -1e4f), 1e4f);
      }
    }
  }
  if constexpr (PHASE == 1) {
    #pragma unroll
    for (int s = 0; s < 8; ++s) {
      Aprod[smb + (size_t)s * M_] = P[s];
      Hend[smb + (size_t)s * M_]  = h[s];
    }
  }
}

__global__ __launch_bounds__(256) void carry_kernel(
    float* __restrict__ Aprod, const float* __restrict__ Hend)
{
  const int idx = blockIdx.x * 256 + threadIdx.x;
  const int b = idx / MS_;
  const int sm = idx - b * MS_;
  float h = 0.f;
  #pragma unroll 16
  for (int c = 0; c < NCF; ++c) {
    const size_t o = ((size_t)b * NCF + c) * MS_ + sm;
    const float a  = Aprod[o];
    const float he = Hend[o];
    Aprod[o] = h;
    h = fmaf(a, h, he);
  }
}

// --------------------------------------------------------------------------
extern "C" void kernel_launch(void* const* d_in, const int* in_sizes, int n_in,
                              void* d_out, int out_size, void* d_ws, size_t ws_size,
                              hipStream_t stream)
{
  const float* u     = (const float*)d_in[0];
  const float* delta = (const float*)d_in[1];
  const float* dt_w  = (const float*)d_in[2];
  const float* dt_b  = (const float*)d_in[3];
  const float* A_log = (const float*)d_in[4];
  const float* B_w   = (const float*)d_in[5];
  const float* C_w   = (const float*)d_in[6];
  const float* D     = (const float*)d_in[7];
  float* out = (float*)d_out;
  float* ws  = (float*)d_ws;

  // Co-residency check for the cooperative path (768 blocks needed).
  int maxB = 0;
  hipOccupancyMaxActiveBlocksPerMultiprocessor(&maxB, fused_kernel, 256, 0);
  hipDeviceProp_t* unused = nullptr; (void)unused;
  const bool coop_ok = (maxB * 256 >= FGRID);   // 256 CUs on MI355X

  if (coop_ok) {
    // ws layout for fused path
    float* part  = ws;                                   // 128*32*32*8 = 1,048,576
    float* Bm_g  = part + (size_t)128 * FCL * 32 * 8;    // 65,536
    float* Cm_g  = Bm_g + (size_t)B_ * T_ * S_;          // 65,536
    float* Aprod = Cm_g + (size_t)B_ * T_ * S_;          // 1,572,864
    float* Hend  = Aprod + (size_t)B_ * FNC * MS_;       // 1,572,864  (~17.3 MB total)
    void* args[] = {(void*)&u, (void*)&delta, (void*)&dt_w, (void*)&dt_b,
                    (void*)&A_log, (void*)&B_w, (void*)&C_w, (void*)&D,
                    (void*)&out, (void*)&part, (void*)&Bm_g, (void*)&Cm_g,
                    (void*)&Aprod, (void*)&Hend};
    hipLaunchCooperativeKernel((const void*)fused_kernel, dim3(FGRID), dim3(256),
                               args, 0, stream);
  } else {
    const size_t fl_dt = (size_t)B_ * T_ * M_;
    const size_t fl_bc = (size_t)B_ * T_ * S_;
    const size_t fl_sm = (size_t)B_ * NCF * MS_;
    float* dt_ws = ws;
    float* Bm    = dt_ws + fl_dt;
    float* Cm    = Bm + fl_bc;
    float* Aprod = Cm + fl_bc;
    float* Hend  = Aprod + fl_sm;
    dt_kernel<<<dim3(M_ / 64, (B_ * T_) / 64), 256, 0, stream>>>(delta, dt_w, dt_b, dt_ws);
    bc_kernel<<<dim3((B_ * T_) / 8), 512, 0, stream>>>(u, B_w, C_w, Bm, Cm);
    scan_kernel<1><<<dim3(M_ / 64, NCF, B_), 128, 0, stream>>>(
        dt_ws, u, Bm, Cm, A_log, D, Aprod, Hend, nullptr);
    carry_kernel<<<dim3((B_ * MS_) / 256), 256, 0, stream>>>(Aprod, Hend);
    scan_kernel<3><<<dim3(M_ / 64, NCF, B_), 128, 0, stream>>>(
        dt_ws, u, Bm, Cm, A_log, D, Aprod, Hend, out);
  }
}